// Round 9
// baseline (173.201 us; speedup 1.0000x reference)
//
#include <hip/hip_runtime.h>

typedef unsigned short u16;
typedef unsigned int uint;
typedef __attribute__((ext_vector_type(4))) float floatx4;
typedef __attribute__((ext_vector_type(8))) short shortx8;

// ---------- helpers ----------
__device__ __forceinline__ u16 f2b(float f) {
    unsigned int u = __float_as_uint(f);
    unsigned int r = (u + 0x7fffu + ((u >> 16) & 1u)) >> 16;
    return (u16)r;
}
__device__ __forceinline__ float b2f(u16 u) {
    return __uint_as_float(((unsigned int)u) << 16);
}
__device__ __forceinline__ void gl_lds16(const u16* g, u16* l) {
    __builtin_amdgcn_global_load_lds(
        (const __attribute__((address_space(1))) void*)g,
        (__attribute__((address_space(3))) void*)l, 16, 0, 0);
}
__device__ __forceinline__ float gelu_f(float v) {
    float e = __expf(1.59576912f * v * (1.0f + 0.044715f * v * v));
    return v * e / (e + 1.0f);
}

// ---------- wave-per-row LN (C=512), fp32 in ----------
__device__ __forceinline__ void ln_row_wave_f32(const float* __restrict__ x,
                                                const float* __restrict__ w,
                                                const float* __restrict__ b,
                                                u16* __restrict__ out, int row) {
    int lane = threadIdx.x & 63;
    const float4* xr = (const float4*)(x + (size_t)row * 512);
    float4 v0 = xr[lane * 2], v1 = xr[lane * 2 + 1];
    float s = v0.x + v0.y + v0.z + v0.w + v1.x + v1.y + v1.z + v1.w;
    float s2 = v0.x * v0.x + v0.y * v0.y + v0.z * v0.z + v0.w * v0.w +
               v1.x * v1.x + v1.y * v1.y + v1.z * v1.z + v1.w * v1.w;
    #pragma unroll
    for (int o = 32; o > 0; o >>= 1) {
        s += __shfl_xor(s, o, 64);
        s2 += __shfl_xor(s2, o, 64);
    }
    float mu = s * (1.0f / 512.0f);
    float var = s2 * (1.0f / 512.0f) - mu * mu;
    float rstd = rsqrtf(var + 1e-5f);
    const float4* wr = (const float4*)w;
    const float4* br = (const float4*)b;
    float4 w0 = wr[lane * 2], w1 = wr[lane * 2 + 1];
    float4 b0 = br[lane * 2], b1 = br[lane * 2 + 1];
    uint4 o4;
    o4.x = (uint)f2b((v0.x - mu) * rstd * w0.x + b0.x) |
           ((uint)f2b((v0.y - mu) * rstd * w0.y + b0.y) << 16);
    o4.y = (uint)f2b((v0.z - mu) * rstd * w0.z + b0.z) |
           ((uint)f2b((v0.w - mu) * rstd * w0.w + b0.w) << 16);
    o4.z = (uint)f2b((v1.x - mu) * rstd * w1.x + b1.x) |
           ((uint)f2b((v1.y - mu) * rstd * w1.y + b1.y) << 16);
    o4.w = (uint)f2b((v1.z - mu) * rstd * w1.z + b1.z) |
           ((uint)f2b((v1.w - mu) * rstd * w1.w + b1.w) << 16);
    ((uint4*)(out + (size_t)row * 512))[lane] = o4;
}

// ---------- LN2: bf16 input, wave-per-row, 4 rows/block ----------
__global__ __launch_bounds__(256) void ln_kernel_b(const u16* __restrict__ x,
                                                   const float* __restrict__ w,
                                                   const float* __restrict__ b,
                                                   u16* __restrict__ out) {
    int row = blockIdx.x * 4 + (threadIdx.x >> 6);
    int lane = threadIdx.x & 63;
    uint4 p = ((const uint4*)(x + (size_t)row * 512))[lane];
    float v[8];
    v[0] = b2f((u16)(p.x & 0xffffu)); v[1] = b2f((u16)(p.x >> 16));
    v[2] = b2f((u16)(p.y & 0xffffu)); v[3] = b2f((u16)(p.y >> 16));
    v[4] = b2f((u16)(p.z & 0xffffu)); v[5] = b2f((u16)(p.z >> 16));
    v[6] = b2f((u16)(p.w & 0xffffu)); v[7] = b2f((u16)(p.w >> 16));
    float s = 0.f, s2 = 0.f;
    #pragma unroll
    for (int i = 0; i < 8; i++) { s += v[i]; s2 += v[i] * v[i]; }
    #pragma unroll
    for (int o = 32; o > 0; o >>= 1) {
        s += __shfl_xor(s, o, 64);
        s2 += __shfl_xor(s2, o, 64);
    }
    float mu = s * (1.0f / 512.0f);
    float var = s2 * (1.0f / 512.0f) - mu * mu;
    float rstd = rsqrtf(var + 1e-5f);
    const float4* wr = (const float4*)w;
    const float4* br = (const float4*)b;
    float4 w0 = wr[lane * 2], w1 = wr[lane * 2 + 1];
    float4 b0 = br[lane * 2], b1 = br[lane * 2 + 1];
    float o8[8];
    o8[0] = (v[0] - mu) * rstd * w0.x + b0.x;
    o8[1] = (v[1] - mu) * rstd * w0.y + b0.y;
    o8[2] = (v[2] - mu) * rstd * w0.z + b0.z;
    o8[3] = (v[3] - mu) * rstd * w0.w + b0.w;
    o8[4] = (v[4] - mu) * rstd * w1.x + b1.x;
    o8[5] = (v[5] - mu) * rstd * w1.y + b1.y;
    o8[6] = (v[6] - mu) * rstd * w1.z + b1.z;
    o8[7] = (v[7] - mu) * rstd * w1.w + b1.w;
    uint4 o4;
    o4.x = (uint)f2b(o8[0]) | ((uint)f2b(o8[1]) << 16);
    o4.y = (uint)f2b(o8[2]) | ((uint)f2b(o8[3]) << 16);
    o4.z = (uint)f2b(o8[4]) | ((uint)f2b(o8[5]) << 16);
    o4.w = (uint)f2b(o8[6]) | ((uint)f2b(o8[7]) << 16);
    ((uint4*)(out + (size_t)row * 512))[lane] = o4;
}

// ---------- fused prep: cvt 4 weights + LN1 ----------
__global__ __launch_bounds__(256) void prep_kernel(
    const float* __restrict__ qkvw, u16* __restrict__ wq,
    const float* __restrict__ projw, u16* __restrict__ wp,
    const float* __restrict__ fc1w, u16* __restrict__ w1,
    const float* __restrict__ fc2w, u16* __restrict__ w2,
    const float* __restrict__ x, const float* __restrict__ n1w,
    const float* __restrict__ n1b, u16* __restrict__ hb) {
    int bi = blockIdx.x;
    if (bi < 3072) {
        const float* src;
        u16* dst;
        int i0;
        if (bi < 768)       { src = qkvw; dst = wq; i0 = bi; }
        else if (bi < 1024) { src = projw; dst = wp; i0 = bi - 768; }
        else if (bi < 2048) { src = fc1w; dst = w1; i0 = bi - 1024; }
        else                { src = fc2w; dst = w2; i0 = bi - 2048; }
        int i = i0 * 256 + threadIdx.x;
        float4 v = ((const float4*)src)[i];
        uint2 o;
        o.x = (uint)f2b(v.x) | ((uint)f2b(v.y) << 16);
        o.y = (uint)f2b(v.z) | ((uint)f2b(v.w) << 16);
        ((uint2*)dst)[i] = o;
    } else {
        int row = (bi - 3072) * 4 + (threadIdx.x >> 6);
        ln_row_wave_f32(x, n1w, n1b, hb, row);
    }
}

// ---------- GEMM A: m97-exact. 16x16x32, MI=NI=4, 128x128, BK=64,
// single-buffered 32 KB LDS -> 3 blocks/CU (m114 inter-block overlap hides
// the barrier drain better than intra-block dbuf at 2/CU).
// EPI: 0 bias->bf16 | 2 bias+GELU->bf16
template <int EPI>
__global__ __launch_bounds__(256, 3) void gemm16(const u16* __restrict__ A,
                                                 const u16* __restrict__ W,
                                                 const float* __restrict__ bias,
                                                 u16* __restrict__ outB,
                                                 int M, int Nn, int K) {
    __shared__ u16 a_s[128 * 64];
    __shared__ u16 b_s[128 * 64];

    int tid = threadIdx.x;
    int wid = tid >> 6, lane = tid & 63;
    int wm = wid >> 1, wn = wid & 1;
    int m_blk = blockIdx.x * 128;         // m fastest: same-XCD blocks share B-strip
    int n_blk = blockIdx.y * 128;
    int lr = lane & 15;
    int lkc = lane >> 4;

    floatx4 acc[4][4];
    #pragma unroll
    for (int i = 0; i < 4; i++)
        #pragma unroll
        for (int j = 0; j < 4; j++) acc[i][j] = (floatx4){0.f, 0.f, 0.f, 0.f};

    const u16* Ag = A + (size_t)m_blk * K;
    const u16* Wg = W + (size_t)n_blk * K;

    int srow = tid >> 3;
    int skc = (tid & 7) ^ (srow & 7);

    for (int k0 = 0; k0 < K; k0 += 64) {
        #pragma unroll
        for (int p = 0; p < 4; p++)
            gl_lds16(Ag + (size_t)(p * 32 + srow) * K + k0 + skc * 8,
                     a_s + (p * 256 + tid) * 8);
        #pragma unroll
        for (int p = 0; p < 4; p++)
            gl_lds16(Wg + (size_t)(p * 32 + srow) * K + k0 + skc * 8,
                     b_s + (p * 256 + tid) * 8);
        __syncthreads();
        #pragma unroll
        for (int s = 0; s < 2; s++) {
            int kc = s * 4 + lkc;
            shortx8 af[4], bf[4];
            #pragma unroll
            for (int i = 0; i < 4; i++) {
                int row = wm * 64 + i * 16 + lr;
                af[i] = *(const shortx8*)(a_s + (row * 8 + (kc ^ (row & 7))) * 8);
            }
            #pragma unroll
            for (int j = 0; j < 4; j++) {
                int row = wn * 64 + j * 16 + lr;
                bf[j] = *(const shortx8*)(b_s + (row * 8 + (kc ^ (row & 7))) * 8);
            }
            #pragma unroll
            for (int i = 0; i < 4; i++)
                #pragma unroll
                for (int j = 0; j < 4; j++)
                    acc[i][j] = __builtin_amdgcn_mfma_f32_16x16x32_bf16(
                        af[i], bf[j], acc[i][j], 0, 0, 0);
        }
        __syncthreads();
    }

    int col_l = lane & 15;
    int row_base = (lane >> 4) * 4;
    #pragma unroll
    for (int nj = 0; nj < 4; nj++) {
        int col = n_blk + wn * 64 + nj * 16 + col_l;
        float bv = bias[col];
        #pragma unroll
        for (int mi = 0; mi < 4; mi++) {
            #pragma unroll
            for (int r = 0; r < 4; r++) {
                int row = m_blk + wm * 64 + mi * 16 + row_base + r;
                size_t off = (size_t)row * Nn + col;
                float v = acc[mi][nj][r] + bv;
                outB[off] = f2b(EPI == 2 ? gelu_f(v) : v);
            }
        }
    }
}

// ---------- GEMM B: 64x64 block, MI=NI=2 (16x16), BK=64, single-buffered
// 16 KB LDS -> 4 blocks/CU (launch_bounds). LDS-bound regime (32x32 wave
// tile): TLP is the mitigation. EPI: 1 bias+residF32->bf16 | 3 bias+residB16->fp32
template <int EPI>
__global__ __launch_bounds__(256, 4) void gemm64(const u16* __restrict__ A,
                                                 const u16* __restrict__ W,
                                                 const float* __restrict__ bias,
                                                 const float* __restrict__ residF,
                                                 const u16* __restrict__ residB,
                                                 float* __restrict__ outF,
                                                 u16* __restrict__ outB,
                                                 int M, int Nn, int K) {
    __shared__ u16 a_s[64 * 64];
    __shared__ u16 b_s[64 * 64];

    int tid = threadIdx.x;
    int wid = tid >> 6, lane = tid & 63;
    int wm = wid >> 1, wn = wid & 1;
    int m_blk = blockIdx.x * 64;
    int n_blk = blockIdx.y * 64;
    int lr = lane & 15;
    int lkc = lane >> 4;

    floatx4 acc[2][2];
    #pragma unroll
    for (int i = 0; i < 2; i++)
        #pragma unroll
        for (int j = 0; j < 2; j++) acc[i][j] = (floatx4){0.f, 0.f, 0.f, 0.f};

    const u16* Ag = A + (size_t)m_blk * K;
    const u16* Wg = W + (size_t)n_blk * K;

    int srow = tid >> 3;
    int skc = (tid & 7) ^ (srow & 7);

    for (int k0 = 0; k0 < K; k0 += 64) {
        #pragma unroll
        for (int p = 0; p < 2; p++)
            gl_lds16(Ag + (size_t)(p * 32 + srow) * K + k0 + skc * 8,
                     a_s + (p * 256 + tid) * 8);
        #pragma unroll
        for (int p = 0; p < 2; p++)
            gl_lds16(Wg + (size_t)(p * 32 + srow) * K + k0 + skc * 8,
                     b_s + (p * 256 + tid) * 8);
        __syncthreads();
        #pragma unroll
        for (int s = 0; s < 2; s++) {
            int kc = s * 4 + lkc;
            shortx8 af[2], bf[2];
            #pragma unroll
            for (int i = 0; i < 2; i++) {
                int row = wm * 32 + i * 16 + lr;
                af[i] = *(const shortx8*)(a_s + (row * 8 + (kc ^ (row & 7))) * 8);
            }
            #pragma unroll
            for (int j = 0; j < 2; j++) {
                int row = wn * 32 + j * 16 + lr;
                bf[j] = *(const shortx8*)(b_s + (row * 8 + (kc ^ (row & 7))) * 8);
            }
            #pragma unroll
            for (int i = 0; i < 2; i++)
                #pragma unroll
                for (int j = 0; j < 2; j++)
                    acc[i][j] = __builtin_amdgcn_mfma_f32_16x16x32_bf16(
                        af[i], bf[j], acc[i][j], 0, 0, 0);
        }
        __syncthreads();
    }

    int col_l = lane & 15;
    int row_base = (lane >> 4) * 4;
    #pragma unroll
    for (int nj = 0; nj < 2; nj++) {
        int col = n_blk + wn * 32 + nj * 16 + col_l;
        float bv = bias[col];
        #pragma unroll
        for (int mi = 0; mi < 2; mi++) {
            #pragma unroll
            for (int r = 0; r < 4; r++) {
                int row = m_blk + wm * 32 + mi * 16 + row_base + r;
                size_t off = (size_t)row * Nn + col;
                float v = acc[mi][nj][r] + bv;
                if (EPI == 1) outB[off] = f2b(v + residF[off]);
                else          outF[off] = v + b2f(residB[off]);
            }
        }
    }
}

// ---------- windowed attention, MFMA flash-style (unchanged) ----------
__global__ __launch_bounds__(256) void attn_kernel(const u16* __restrict__ qkv,
                                                   const float* __restrict__ rel_bias,
                                                   u16* __restrict__ out) {
    __shared__ u16 k_s[128][72];
    __shared__ u16 v_t[64][152];
    __shared__ u16 p_s[4][16][104];
    __shared__ float s_bias[64];

    int bx = blockIdx.x;
    int n = bx >> 8;
    int h = (bx >> 5) & 7;
    int t0 = (bx & 31) << 6;
    int tid = threadIdx.x, wid = tid >> 6, lane = tid & 63;
    int col = lane & 15, rq = lane >> 4;

    const u16* qrow = qkv + (size_t)(n * 2048 + t0 + wid * 16 + col) * 1536 + h * 64 + rq * 8;
    shortx8 qf0 = *(const shortx8*)qrow;
    shortx8 qf1 = *(const shortx8*)(qrow + 32);

    if (tid < 63) s_bias[tid] = rel_bias[h * 63 + tid];
    if (tid == 63) s_bias[63] = 0.f;

    const uint* qkv_u = (const uint*)qkv;
    for (int idx = tid; idx < 128 * 32; idx += 256) {
        int row = idx >> 5, j = idx & 31;
        int pos = t0 - 31 + row;
        uint kv = 0;
        if (pos >= 0 && pos < 2048)
            kv = qkv_u[(size_t)(n * 2048 + pos) * 768 + 256 + h * 32 + j];
        *(uint*)&k_s[row][j * 2] = kv;
    }
    for (int idx = tid; idx < 144 * 32; idx += 256) {
        int row = idx >> 5, j = idx & 31;
        int pos = t0 - 31 + row;
        uint vv = 0;
        if (pos >= 0 && pos < 2048)
            vv = qkv_u[(size_t)(n * 2048 + pos) * 768 + 512 + h * 32 + j];
        v_t[2 * j][row] = (u16)(vv & 0xffffu);
        v_t[2 * j + 1][row] = (u16)(vv >> 16);
    }
    __syncthreads();

    floatx4 S[5];
    #pragma unroll
    for (int nt = 0; nt < 5; nt++) S[nt] = (floatx4){0.f, 0.f, 0.f, 0.f};
    #pragma unroll
    for (int nt = 0; nt < 5; nt++) {
        const u16* kb = &k_s[wid * 16 + nt * 16 + col][rq * 8];
        shortx8 b0 = *(const shortx8*)kb;
        shortx8 b1 = *(const shortx8*)(kb + 32);
        S[nt] = __builtin_amdgcn_mfma_f32_16x16x32_bf16(qf0, b0, S[nt], 0, 0, 0);
        S[nt] = __builtin_amdgcn_mfma_f32_16x16x32_bf16(qf1, b1, S[nt], 0, 0, 0);
    }

    #pragma unroll
    for (int r = 0; r < 4; r++) {
        int t_row = rq * 4 + r;
        float sc[5];
        float mx = -1e30f;
        #pragma unroll
        for (int nt = 0; nt < 5; nt++) {
            int w = nt * 16 + col - t_row;
            int pos_abs = t0 - 31 + wid * 16 + nt * 16 + col;
            float v;
            if (w < 0 || w > 62) {
                v = -1e30f;
            } else {
                v = S[nt][r] * 0.125f + s_bias[w];
                if (pos_abs < 0 || pos_abs >= 2048) v -= 100.f;
            }
            sc[nt] = v;
            mx = fmaxf(mx, v);
        }
        #pragma unroll
        for (int o = 1; o < 16; o <<= 1) mx = fmaxf(mx, __shfl_xor(mx, o, 64));
        float l = 0.f;
        #pragma unroll
        for (int nt = 0; nt < 5; nt++) {
            sc[nt] = __expf(sc[nt] - mx);
            l += sc[nt];
        }
        #pragma unroll
        for (int o = 1; o < 16; o <<= 1) l += __shfl_xor(l, o, 64);
        float inv = 1.0f / l;
        #pragma unroll
        for (int nt = 0; nt < 5; nt++)
            p_s[wid][t_row][nt * 16 + col] = f2b(sc[nt] * inv);
        p_s[wid][t_row][80 + col] = 0;
    }
    __syncthreads();

    floatx4 O[4];
    #pragma unroll
    for (int dt = 0; dt < 4; dt++) O[dt] = (floatx4){0.f, 0.f, 0.f, 0.f};
    const u16* pr = &p_s[wid][col][rq * 8];
    shortx8 a0 = *(const shortx8*)pr;
    shortx8 a1 = *(const shortx8*)(pr + 32);
    shortx8 a2 = *(const shortx8*)(pr + 64);
    #pragma unroll
    for (int dt = 0; dt < 4; dt++) {
        const u16* vb = &v_t[dt * 16 + col][wid * 16 + rq * 8];
        shortx8 b0 = *(const shortx8*)vb;
        shortx8 b1 = *(const shortx8*)(vb + 32);
        shortx8 b2 = *(const shortx8*)(vb + 64);
        O[dt] = __builtin_amdgcn_mfma_f32_16x16x32_bf16(a0, b0, O[dt], 0, 0, 0);
        O[dt] = __builtin_amdgcn_mfma_f32_16x16x32_bf16(a1, b1, O[dt], 0, 0, 0);
        O[dt] = __builtin_amdgcn_mfma_f32_16x16x32_bf16(a2, b2, O[dt], 0, 0, 0);
    }

    #pragma unroll
    for (int dt = 0; dt < 4; dt++) {
        #pragma unroll
        for (int r = 0; r < 4; r++) {
            int t_row = rq * 4 + r;
            out[(size_t)(n * 2048 + t0 + wid * 16 + t_row) * 512 + h * 64 + dt * 16 + col] =
                f2b(O[dt][r]);
        }
    }
}

// ---------- launcher ----------
extern "C" void kernel_launch(void* const* d_in, const int* in_sizes, int n_in,
                              void* d_out, int out_size, void* d_ws, size_t ws_size,
                              hipStream_t stream) {
    const float* x     = (const float*)d_in[0];
    const float* n1w   = (const float*)d_in[1];
    const float* n1b   = (const float*)d_in[2];
    const float* qkvw  = (const float*)d_in[3];
    const float* qkvbv = (const float*)d_in[4];
    const float* relb  = (const float*)d_in[5];
    const float* projw = (const float*)d_in[6];
    const float* projb = (const float*)d_in[7];
    const float* n2w   = (const float*)d_in[8];
    const float* n2b   = (const float*)d_in[9];
    const float* fc1w  = (const float*)d_in[10];
    const float* fc1b  = (const float*)d_in[11];
    const float* fc2w  = (const float*)d_in[12];
    const float* fc2b  = (const float*)d_in[13];
    float* out = (float*)d_out;

    char* p = (char*)d_ws;
    u16* wq   = (u16*)p;  p += (size_t)786432 * 2;   // qkv_w bf16 (1536x512)
    u16* wp   = (u16*)p;  p += (size_t)262144 * 2;   // proj_w bf16 (512x512)
    u16* w1   = (u16*)p;  p += (size_t)1048576 * 2;  // fc1_w bf16 (2048x512)
    u16* w2   = (u16*)p;  p += (size_t)1048576 * 2;  // fc2_w bf16 (512x2048)
    u16* hb   = (u16*)p;  p += (size_t)2097152 * 2;  // h / h2 bf16 (4096x512)
    u16* qkvb = (u16*)p;  p += (size_t)6291456 * 2;  // qkv bf16 (4096x1536)
    u16* attb = (u16*)p;  p += (size_t)2097152 * 2;  // attn out bf16 (4096x512)
    u16* x2b  = (u16*)p;  p += (size_t)2097152 * 2;  // x + proj(attn), bf16
    u16* mb   = (u16*)p;  p += (size_t)8388608 * 2;  // gelu(fc1) bf16 (4096x2048)

    prep_kernel<<<4096, 256, 0, stream>>>(qkvw, wq, projw, wp, fc1w, w1, fc2w, w2,
                                          x, n1w, n1b, hb);
    // qkv: 4096x1536, K=512; 128x128, 3 blocks/CU
    gemm16<0><<<dim3(32, 12), 256, 0, stream>>>(hb, wq, qkvbv, qkvb, 4096, 1536, 512);
    attn_kernel<<<512, 256, 0, stream>>>(qkvb, relb, attb);
    // proj: 4096x512, K=512; 64x64, 4 blocks/CU; x2 = x + proj (bf16)
    gemm64<1><<<dim3(64, 8), 256, 0, stream>>>(attb, wp, projb, x, nullptr,
                                               nullptr, x2b, 4096, 512, 512);
    ln_kernel_b<<<1024, 256, 0, stream>>>(x2b, n2w, n2b, hb);
    // fc1: 4096x2048, K=512
    gemm16<2><<<dim3(32, 16), 256, 0, stream>>>(hb, w1, fc1b, mb, 4096, 2048, 512);
    // fc2: 4096x512, K=2048; out = x2 + fc2 (fp32)
    gemm64<3><<<dim3(64, 8), 256, 0, stream>>>(mb, w2, fc2b, nullptr, x2b,
                                               out, nullptr, 4096, 512, 2048);
}

// Round 10
// 165.960 us; speedup vs baseline: 1.0436x; 1.0436x over previous
//
#include <hip/hip_runtime.h>

typedef unsigned short u16;
typedef unsigned int uint;
typedef __attribute__((ext_vector_type(4))) float floatx4;
typedef __attribute__((ext_vector_type(16))) float floatx16;
typedef __attribute__((ext_vector_type(8))) short shortx8;

// ---------- helpers ----------
__device__ __forceinline__ u16 f2b(float f) {
    unsigned int u = __float_as_uint(f);
    unsigned int r = (u + 0x7fffu + ((u >> 16) & 1u)) >> 16;
    return (u16)r;
}
__device__ __forceinline__ float b2f(u16 u) {
    return __uint_as_float(((unsigned int)u) << 16);
}
__device__ __forceinline__ void gl_lds16(const u16* g, u16* l) {
    __builtin_amdgcn_global_load_lds(
        (const __attribute__((address_space(1))) void*)g,
        (__attribute__((address_space(3))) void*)l, 16, 0, 0);
}
__device__ __forceinline__ float gelu_f(float v) {
    float e = __expf(1.59576912f * v * (1.0f + 0.044715f * v * v));
    return v * e / (e + 1.0f);
}

// ---------- wave-per-row LN (C=512): 8 elems/lane, shuffle-only ----------
__device__ __forceinline__ void ln_row_wave_f32(const float* __restrict__ x,
                                                const float* __restrict__ w,
                                                const float* __restrict__ b,
                                                u16* __restrict__ out, int row) {
    int lane = threadIdx.x & 63;
    const float4* xr = (const float4*)(x + (size_t)row * 512);
    float4 v0 = xr[lane * 2], v1 = xr[lane * 2 + 1];
    float s = v0.x + v0.y + v0.z + v0.w + v1.x + v1.y + v1.z + v1.w;
    float s2 = v0.x * v0.x + v0.y * v0.y + v0.z * v0.z + v0.w * v0.w +
               v1.x * v1.x + v1.y * v1.y + v1.z * v1.z + v1.w * v1.w;
    #pragma unroll
    for (int o = 32; o > 0; o >>= 1) {
        s += __shfl_xor(s, o, 64);
        s2 += __shfl_xor(s2, o, 64);
    }
    float mu = s * (1.0f / 512.0f);
    float var = s2 * (1.0f / 512.0f) - mu * mu;
    float rstd = rsqrtf(var + 1e-5f);
    const float4* wr = (const float4*)w;
    const float4* br = (const float4*)b;
    float4 w0 = wr[lane * 2], w1 = wr[lane * 2 + 1];
    float4 b0 = br[lane * 2], b1 = br[lane * 2 + 1];
    uint4 o4;
    o4.x = (uint)f2b((v0.x - mu) * rstd * w0.x + b0.x) |
           ((uint)f2b((v0.y - mu) * rstd * w0.y + b0.y) << 16);
    o4.y = (uint)f2b((v0.z - mu) * rstd * w0.z + b0.z) |
           ((uint)f2b((v0.w - mu) * rstd * w0.w + b0.w) << 16);
    o4.z = (uint)f2b((v1.x - mu) * rstd * w1.x + b1.x) |
           ((uint)f2b((v1.y - mu) * rstd * w1.y + b1.y) << 16);
    o4.w = (uint)f2b((v1.z - mu) * rstd * w1.z + b1.z) |
           ((uint)f2b((v1.w - mu) * rstd * w1.w + b1.w) << 16);
    ((uint4*)(out + (size_t)row * 512))[lane] = o4;
}

// ---------- LN2: bf16 input, wave-per-row, 4 rows/block ----------
__global__ __launch_bounds__(256) void ln_kernel_b(const u16* __restrict__ x,
                                                   const float* __restrict__ w,
                                                   const float* __restrict__ b,
                                                   u16* __restrict__ out) {
    int row = blockIdx.x * 4 + (threadIdx.x >> 6);
    int lane = threadIdx.x & 63;
    uint4 p = ((const uint4*)(x + (size_t)row * 512))[lane];
    float v[8];
    v[0] = b2f((u16)(p.x & 0xffffu)); v[1] = b2f((u16)(p.x >> 16));
    v[2] = b2f((u16)(p.y & 0xffffu)); v[3] = b2f((u16)(p.y >> 16));
    v[4] = b2f((u16)(p.z & 0xffffu)); v[5] = b2f((u16)(p.z >> 16));
    v[6] = b2f((u16)(p.w & 0xffffu)); v[7] = b2f((u16)(p.w >> 16));
    float s = 0.f, s2 = 0.f;
    #pragma unroll
    for (int i = 0; i < 8; i++) { s += v[i]; s2 += v[i] * v[i]; }
    #pragma unroll
    for (int o = 32; o > 0; o >>= 1) {
        s += __shfl_xor(s, o, 64);
        s2 += __shfl_xor(s2, o, 64);
    }
    float mu = s * (1.0f / 512.0f);
    float var = s2 * (1.0f / 512.0f) - mu * mu;
    float rstd = rsqrtf(var + 1e-5f);
    const float4* wr = (const float4*)w;
    const float4* br = (const float4*)b;
    float4 w0 = wr[lane * 2], w1 = wr[lane * 2 + 1];
    float4 b0 = br[lane * 2], b1 = br[lane * 2 + 1];
    float o8[8];
    o8[0] = (v[0] - mu) * rstd * w0.x + b0.x;
    o8[1] = (v[1] - mu) * rstd * w0.y + b0.y;
    o8[2] = (v[2] - mu) * rstd * w0.z + b0.z;
    o8[3] = (v[3] - mu) * rstd * w0.w + b0.w;
    o8[4] = (v[4] - mu) * rstd * w1.x + b1.x;
    o8[5] = (v[5] - mu) * rstd * w1.y + b1.y;
    o8[6] = (v[6] - mu) * rstd * w1.z + b1.z;
    o8[7] = (v[7] - mu) * rstd * w1.w + b1.w;
    uint4 o4;
    o4.x = (uint)f2b(o8[0]) | ((uint)f2b(o8[1]) << 16);
    o4.y = (uint)f2b(o8[2]) | ((uint)f2b(o8[3]) << 16);
    o4.z = (uint)f2b(o8[4]) | ((uint)f2b(o8[5]) << 16);
    o4.w = (uint)f2b(o8[6]) | ((uint)f2b(o8[7]) << 16);
    ((uint4*)(out + (size_t)row * 512))[lane] = o4;
}

// ---------- fused prep: cvt 4 weights + LN1 (wave-per-row) ----------
// blocks [0,3072): weight cvt | [3072,4096): LN1, 4 rows per block
__global__ __launch_bounds__(256) void prep_kernel(
    const float* __restrict__ qkvw, u16* __restrict__ wq,
    const float* __restrict__ projw, u16* __restrict__ wp,
    const float* __restrict__ fc1w, u16* __restrict__ w1,
    const float* __restrict__ fc2w, u16* __restrict__ w2,
    const float* __restrict__ x, const float* __restrict__ n1w,
    const float* __restrict__ n1b, u16* __restrict__ hb) {
    int bi = blockIdx.x;
    if (bi < 3072) {
        const float* src;
        u16* dst;
        int i0;
        if (bi < 768)       { src = qkvw; dst = wq; i0 = bi; }
        else if (bi < 1024) { src = projw; dst = wp; i0 = bi - 768; }
        else if (bi < 2048) { src = fc1w; dst = w1; i0 = bi - 1024; }
        else                { src = fc2w; dst = w2; i0 = bi - 2048; }
        int i = i0 * 256 + threadIdx.x;
        float4 v = ((const float4*)src)[i];
        uint2 o;
        o.x = (uint)f2b(v.x) | ((uint)f2b(v.y) << 16);
        o.y = (uint)f2b(v.z) | ((uint)f2b(v.w) << 16);
        ((uint2*)dst)[i] = o;
    } else {
        int row = (bi - 3072) * 4 + (threadIdx.x >> 6);
        ln_row_wave_f32(x, n1w, n1b, hb, row);
    }
}

// ---------- GEMM A: 16x16x32 MFMA, MI=NI=4 (m97 frag reuse), dbuf ----------
// 128x128 block, BK=64, 2x2 waves, wave tile 64x64 as 4x4 16-tiles.
// reads/MFMA = 0.5 (each frag feeds 4 MFMAs). EPI: 0 bias->bf16 | 2 bias+GELU->bf16
// R9 lesson: dbuf@2blk/CU beats single-buf@3-4blk/CU (prefetch-before-compute
// overlap > co-resident-block TLP for synchronized barrier drains).
template <int EPI>
__global__ __launch_bounds__(256, 2) void gemm16(const u16* __restrict__ A,
                                                 const u16* __restrict__ W,
                                                 const float* __restrict__ bias,
                                                 u16* __restrict__ outB,
                                                 int M, int Nn, int K) {
    constexpr int BM = 128, BN = 128, BK = 64;
    __shared__ u16 a_s[2][BM * BK];
    __shared__ u16 b_s[2][BN * BK];

    int tid = threadIdx.x;
    int wid = tid >> 6, lane = tid & 63;
    int wm = wid >> 1, wn = wid & 1;
    int m_blk = blockIdx.x * BM;          // m fastest: same-XCD blocks share B-strip
    int n_blk = blockIdx.y * BN;
    int lr = lane & 15;
    int lkc = lane >> 4;                  // 0..3

    floatx4 acc[4][4];
    #pragma unroll
    for (int i = 0; i < 4; i++)
        #pragma unroll
        for (int j = 0; j < 4; j++) acc[i][j] = (floatx4){0.f, 0.f, 0.f, 0.f};

    const u16* Ag = A + (size_t)m_blk * K;
    const u16* Wg = W + (size_t)n_blk * K;

    int srow = tid >> 3;                  // staging: 4 chunks/thread, rows of 8 chunks
    int skc = (tid & 7) ^ (srow & 7);

    auto stage = [&](int k0, int buf) {
        #pragma unroll
        for (int p = 0; p < 4; p++)
            gl_lds16(Ag + (size_t)(p * 32 + srow) * K + k0 + skc * 8,
                     a_s[buf] + (p * 256 + tid) * 8);
        #pragma unroll
        for (int p = 0; p < 4; p++)
            gl_lds16(Wg + (size_t)(p * 32 + srow) * K + k0 + skc * 8,
                     b_s[buf] + (p * 256 + tid) * 8);
    };

    stage(0, 0);
    int nit = K >> 6;
    for (int it = 0; it < nit; it++) {
        __syncthreads();
        if (it + 1 < nit) stage((it + 1) << 6, (it + 1) & 1);
        int cb = it & 1;
        #pragma unroll
        for (int s = 0; s < 2; s++) {     // two K=32 sub-tiles
            int kc = s * 4 + lkc;
            shortx8 af[4], bf[4];
            #pragma unroll
            for (int i = 0; i < 4; i++) {
                int row = wm * 64 + i * 16 + lr;
                af[i] = *(const shortx8*)(a_s[cb] + (row * 8 + (kc ^ (row & 7))) * 8);
            }
            #pragma unroll
            for (int j = 0; j < 4; j++) {
                int row = wn * 64 + j * 16 + lr;
                bf[j] = *(const shortx8*)(b_s[cb] + (row * 8 + (kc ^ (row & 7))) * 8);
            }
            #pragma unroll
            for (int i = 0; i < 4; i++)
                #pragma unroll
                for (int j = 0; j < 4; j++)
                    acc[i][j] = __builtin_amdgcn_mfma_f32_16x16x32_bf16(
                        af[i], bf[j], acc[i][j], 0, 0, 0);
        }
    }

    // C/D: col = lane&15, row = (lane>>4)*4 + r
    int col_l = lane & 15;
    int row_base = (lane >> 4) * 4;
    #pragma unroll
    for (int nj = 0; nj < 4; nj++) {
        int col = n_blk + wn * 64 + nj * 16 + col_l;
        float bv = bias[col];
        #pragma unroll
        for (int mi = 0; mi < 4; mi++) {
            #pragma unroll
            for (int r = 0; r < 4; r++) {
                int row = m_blk + wm * 64 + mi * 16 + row_base + r;
                size_t off = (size_t)row * Nn + col;
                float v = acc[mi][nj][r] + bv;
                outB[off] = f2b(EPI == 2 ? gelu_f(v) : v);
            }
        }
    }
}

// ---------- GEMM B: 32x32x16, 64x64 block, BK=128, dbuf (N=512 GEMMs) ----------
// EPI: 1 bias+residF32->bf16 | 3 bias+residB16->fp32 (d_out)
template <int EPI>
__global__ __launch_bounds__(256, 2) void gemm32(const u16* __restrict__ A,
                                                 const u16* __restrict__ W,
                                                 const float* __restrict__ bias,
                                                 const float* __restrict__ residF,
                                                 const u16* __restrict__ residB,
                                                 float* __restrict__ outF,
                                                 u16* __restrict__ outB,
                                                 int M, int Nn, int K) {
    constexpr int BM = 64, BN = 64, BK = 128;
    constexpr int CPR = BK / 8, KMSK = CPR - 1;
    __shared__ u16 a_s[2][BM * BK];
    __shared__ u16 b_s[2][BN * BK];

    int tid = threadIdx.x;
    int wid = tid >> 6, lane = tid & 63;
    int wm = wid >> 1, wn = wid & 1;
    int m_blk = blockIdx.x * BM;
    int n_blk = blockIdx.y * BN;
    int lr = lane & 31;
    int lk = lane >> 5;

    floatx16 acc;
    #pragma unroll
    for (int r = 0; r < 16; r++) acc[r] = 0.f;

    const u16* Ag = A + (size_t)m_blk * K;
    const u16* Wg = W + (size_t)n_blk * K;

    int srow = tid / CPR;                 // 4 rows per 64 threads
    int skc = (tid & KMSK) ^ (srow & KMSK);

    auto stage = [&](int k0, int buf) {
        #pragma unroll
        for (int p = 0; p < 4; p++)
            gl_lds16(Ag + (size_t)(p * 16 + srow) * K + k0 + skc * 8,
                     a_s[buf] + (p * 256 + tid) * 8);
        #pragma unroll
        for (int p = 0; p < 4; p++)
            gl_lds16(Wg + (size_t)(p * 16 + srow) * K + k0 + skc * 8,
                     b_s[buf] + (p * 256 + tid) * 8);
    };

    stage(0, 0);
    int nit = K / BK;
    for (int it = 0; it < nit; it++) {
        __syncthreads();
        if (it + 1 < nit) stage((it + 1) * BK, (it + 1) & 1);
        int cb = it & 1;
        #pragma unroll
        for (int s = 0; s < BK / 16; s++) {
            int kc = s * 2 + lk;
            int arow = wm * 32 + lr;
            int brow = wn * 32 + lr;
            shortx8 af = *(const shortx8*)(a_s[cb] + (arow * CPR + (kc ^ (arow & KMSK))) * 8);
            shortx8 bf = *(const shortx8*)(b_s[cb] + (brow * CPR + (kc ^ (brow & KMSK))) * 8);
            acc = __builtin_amdgcn_mfma_f32_32x32x16_bf16(af, bf, acc, 0, 0, 0);
        }
    }

    int col_l = lane & 31;
    int row_q = 4 * (lane >> 5);
    int col = n_blk + wn * 32 + col_l;
    float bv = bias[col];
    #pragma unroll
    for (int r = 0; r < 16; r++) {
        int row = m_blk + wm * 32 + (r & 3) + 8 * (r >> 2) + row_q;
        size_t off = (size_t)row * Nn + col;
        float v = acc[r] + bv;
        if (EPI == 1) outB[off] = f2b(v + residF[off]);
        else          outF[off] = v + b2f(residB[off]);
    }
}

// ---------- windowed attention, MFMA flash-style ----------
__global__ __launch_bounds__(256) void attn_kernel(const u16* __restrict__ qkv,
                                                   const float* __restrict__ rel_bias,
                                                   u16* __restrict__ out) {
    __shared__ u16 k_s[128][72];
    __shared__ u16 v_t[64][152];
    __shared__ u16 p_s[4][16][104];
    __shared__ float s_bias[64];

    int bx = blockIdx.x;
    int n = bx >> 8;
    int h = (bx >> 5) & 7;
    int t0 = (bx & 31) << 6;
    int tid = threadIdx.x, wid = tid >> 6, lane = tid & 63;
    int col = lane & 15, rq = lane >> 4;

    const u16* qrow = qkv + (size_t)(n * 2048 + t0 + wid * 16 + col) * 1536 + h * 64 + rq * 8;
    shortx8 qf0 = *(const shortx8*)qrow;
    shortx8 qf1 = *(const shortx8*)(qrow + 32);

    if (tid < 63) s_bias[tid] = rel_bias[h * 63 + tid];
    if (tid == 63) s_bias[63] = 0.f;

    const uint* qkv_u = (const uint*)qkv;
    for (int idx = tid; idx < 128 * 32; idx += 256) {
        int row = idx >> 5, j = idx & 31;
        int pos = t0 - 31 + row;
        uint kv = 0;
        if (pos >= 0 && pos < 2048)
            kv = qkv_u[(size_t)(n * 2048 + pos) * 768 + 256 + h * 32 + j];
        *(uint*)&k_s[row][j * 2] = kv;
    }
    for (int idx = tid; idx < 144 * 32; idx += 256) {
        int row = idx >> 5, j = idx & 31;
        int pos = t0 - 31 + row;
        uint vv = 0;
        if (pos >= 0 && pos < 2048)
            vv = qkv_u[(size_t)(n * 2048 + pos) * 768 + 512 + h * 32 + j];
        v_t[2 * j][row] = (u16)(vv & 0xffffu);
        v_t[2 * j + 1][row] = (u16)(vv >> 16);
    }
    __syncthreads();

    floatx4 S[5];
    #pragma unroll
    for (int nt = 0; nt < 5; nt++) S[nt] = (floatx4){0.f, 0.f, 0.f, 0.f};
    #pragma unroll
    for (int nt = 0; nt < 5; nt++) {
        const u16* kb = &k_s[wid * 16 + nt * 16 + col][rq * 8];
        shortx8 b0 = *(const shortx8*)kb;
        shortx8 b1 = *(const shortx8*)(kb + 32);
        S[nt] = __builtin_amdgcn_mfma_f32_16x16x32_bf16(qf0, b0, S[nt], 0, 0, 0);
        S[nt] = __builtin_amdgcn_mfma_f32_16x16x32_bf16(qf1, b1, S[nt], 0, 0, 0);
    }

    #pragma unroll
    for (int r = 0; r < 4; r++) {
        int t_row = rq * 4 + r;
        float sc[5];
        float mx = -1e30f;
        #pragma unroll
        for (int nt = 0; nt < 5; nt++) {
            int w = nt * 16 + col - t_row;
            int pos_abs = t0 - 31 + wid * 16 + nt * 16 + col;
            float v;
            if (w < 0 || w > 62) {
                v = -1e30f;
            } else {
                v = S[nt][r] * 0.125f + s_bias[w];
                if (pos_abs < 0 || pos_abs >= 2048) v -= 100.f;
            }
            sc[nt] = v;
            mx = fmaxf(mx, v);
        }
        #pragma unroll
        for (int o = 1; o < 16; o <<= 1) mx = fmaxf(mx, __shfl_xor(mx, o, 64));
        float l = 0.f;
        #pragma unroll
        for (int nt = 0; nt < 5; nt++) {
            sc[nt] = __expf(sc[nt] - mx);
            l += sc[nt];
        }
        #pragma unroll
        for (int o = 1; o < 16; o <<= 1) l += __shfl_xor(l, o, 64);
        float inv = 1.0f / l;
        #pragma unroll
        for (int nt = 0; nt < 5; nt++)
            p_s[wid][t_row][nt * 16 + col] = f2b(sc[nt] * inv);
        p_s[wid][t_row][80 + col] = 0;
    }
    __syncthreads();

    floatx4 O[4];
    #pragma unroll
    for (int dt = 0; dt < 4; dt++) O[dt] = (floatx4){0.f, 0.f, 0.f, 0.f};
    const u16* pr = &p_s[wid][col][rq * 8];
    shortx8 a0 = *(const shortx8*)pr;
    shortx8 a1 = *(const shortx8*)(pr + 32);
    shortx8 a2 = *(const shortx8*)(pr + 64);
    #pragma unroll
    for (int dt = 0; dt < 4; dt++) {
        const u16* vb = &v_t[dt * 16 + col][wid * 16 + rq * 8];
        shortx8 b0 = *(const shortx8*)vb;
        shortx8 b1 = *(const shortx8*)(vb + 32);
        shortx8 b2 = *(const shortx8*)(vb + 64);
        O[dt] = __builtin_amdgcn_mfma_f32_16x16x32_bf16(a0, b0, O[dt], 0, 0, 0);
        O[dt] = __builtin_amdgcn_mfma_f32_16x16x32_bf16(a1, b1, O[dt], 0, 0, 0);
        O[dt] = __builtin_amdgcn_mfma_f32_16x16x32_bf16(a2, b2, O[dt], 0, 0, 0);
    }

    #pragma unroll
    for (int dt = 0; dt < 4; dt++) {
        #pragma unroll
        for (int r = 0; r < 4; r++) {
            int t_row = rq * 4 + r;
            out[(size_t)(n * 2048 + t0 + wid * 16 + t_row) * 512 + h * 64 + dt * 16 + col] =
                f2b(O[dt][r]);
        }
    }
}

// ---------- launcher ----------
extern "C" void kernel_launch(void* const* d_in, const int* in_sizes, int n_in,
                              void* d_out, int out_size, void* d_ws, size_t ws_size,
                              hipStream_t stream) {
    const float* x     = (const float*)d_in[0];
    const float* n1w   = (const float*)d_in[1];
    const float* n1b   = (const float*)d_in[2];
    const float* qkvw  = (const float*)d_in[3];
    const float* qkvbv = (const float*)d_in[4];
    const float* relb  = (const float*)d_in[5];
    const float* projw = (const float*)d_in[6];
    const float* projb = (const float*)d_in[7];
    const float* n2w   = (const float*)d_in[8];
    const float* n2b   = (const float*)d_in[9];
    const float* fc1w  = (const float*)d_in[10];
    const float* fc1b  = (const float*)d_in[11];
    const float* fc2w  = (const float*)d_in[12];
    const float* fc2b  = (const float*)d_in[13];
    float* out = (float*)d_out;

    char* p = (char*)d_ws;
    u16* wq   = (u16*)p;  p += (size_t)786432 * 2;   // qkv_w bf16 (1536x512)
    u16* wp   = (u16*)p;  p += (size_t)262144 * 2;   // proj_w bf16 (512x512)
    u16* w1   = (u16*)p;  p += (size_t)1048576 * 2;  // fc1_w bf16 (2048x512)
    u16* w2   = (u16*)p;  p += (size_t)1048576 * 2;  // fc2_w bf16 (512x2048)
    u16* hb   = (u16*)p;  p += (size_t)2097152 * 2;  // h / h2 bf16 (4096x512)
    u16* qkvb = (u16*)p;  p += (size_t)6291456 * 2;  // qkv bf16 (4096x1536)
    u16* attb = (u16*)p;  p += (size_t)2097152 * 2;  // attn out bf16 (4096x512)
    u16* x2b  = (u16*)p;  p += (size_t)2097152 * 2;  // x + proj(attn), bf16
    u16* mb   = (u16*)p;  p += (size_t)8388608 * 2;  // gelu(fc1) bf16 (4096x2048)

    prep_kernel<<<4096, 256, 0, stream>>>(qkvw, wq, projw, wp, fc1w, w1, fc2w, w2,
                                          x, n1w, n1b, hb);
    // qkv: 4096x1536, K=512; 16x16 MI=NI=4, grid m-fastest
    gemm16<0><<<dim3(32, 12), 256, 0, stream>>>(hb, wq, qkvbv, qkvb, 4096, 1536, 512);
    attn_kernel<<<512, 256, 0, stream>>>(qkvb, relb, attb);
    // proj: 4096x512, K=512; x2 = x + proj (bf16)
    gemm32<1><<<dim3(64, 8), 256, 0, stream>>>(attb, wp, projb, x, nullptr,
                                               nullptr, x2b, 4096, 512, 512);
    ln_kernel_b<<<1024, 256, 0, stream>>>(x2b, n2w, n2b, hb);
    // fc1: 4096x2048, K=512
    gemm16<2><<<dim3(32, 16), 256, 0, stream>>>(hb, w1, fc1b, mb, 4096, 2048, 512);
    // fc2: 4096x512, K=2048; out = x2 + fc2 (fp32)
    gemm32<3><<<dim3(64, 8), 256, 0, stream>>>(mb, w2, fc2b, nullptr, x2b,
                                               out, nullptr, 4096, 512, 2048);
}